// Round 16
// baseline (161.545 us; speedup 1.0000x reference)
//
#include <hip/hip_runtime.h>
#include <hip/hip_bf16.h>

typedef __attribute__((ext_vector_type(4))) float f32x4;
typedef __attribute__((ext_vector_type(16))) float f32x16;
typedef __attribute__((ext_vector_type(8))) short short8;
typedef __attribute__((ext_vector_type(4))) unsigned int uint4v;

// ---------- helpers ----------
__device__ __forceinline__ unsigned short f2bf(float f) {
  unsigned int u = __float_as_uint(f);
  u += 0x7fffu + ((u >> 16) & 1u);   // RNE
  return (unsigned short)(u >> 16);
}

__device__ __forceinline__ void g2lds16(const void* g, void* l) {
  __builtin_amdgcn_global_load_lds(
      (const __attribute__((address_space(1))) void*)g,
      (__attribute__((address_space(3))) void*)l, 16, 0, 0);
}

// ---------- fused prep: f32->bf16 converts + transposed mask bit-pack ----------
// y=0..2: q/k/v cvt. y=3: weights cvt. y=4 (first 512 blocks): mask pack with
// LDS transpose -> coalesced 256B stores per j-row (was: 262K scattered 4B
// stores = ~16x DRAM write amplification).
__global__ __launch_bounds__(256) void prep(
    const float* __restrict__ q, const float* __restrict__ k,
    const float* __restrict__ v, const float* __restrict__ Wq,
    const float* __restrict__ Wk, const float* __restrict__ Wv,
    const float* __restrict__ Wo, const int* __restrict__ mask,
    unsigned short* __restrict__ xq, unsigned short* __restrict__ xk,
    unsigned short* __restrict__ xv, unsigned short* __restrict__ wqb,
    unsigned short* __restrict__ wkb, unsigned short* __restrict__ wvb,
    unsigned short* __restrict__ wob, unsigned int* __restrict__ mbT) {
  const int y = blockIdx.y;
  const int tid = (int)threadIdx.x;
  if (y == 4) {
    const int b = (int)blockIdx.x;
    if (b >= 512) return;
    __shared__ unsigned int mlds[8][64];
    const int kc = b & 7;        // k-chunk of 256 (j32 8..)
    const int rb = b >> 3;       // row-block of 64 tokens
    const int w  = tid >> 6;     // wave 0..3
    const int ln = tid & 63;
    const int kk = kc * 256 + w * 64 + ln;
    for (int lr = 0; lr < 64; ++lr) {
      const int row = rb * 64 + lr;
      const unsigned long long bits = __ballot(mask[(size_t)row * 2048 + kk] != 0);
      if (ln == 0) {
        mlds[w * 2][lr]     = (unsigned int)bits;
        mlds[w * 2 + 1][lr] = (unsigned int)(bits >> 32);
      }
    }
    __syncthreads();
#pragma unroll
    for (int t = tid; t < 512; t += 256) {
      const int jl = t >> 6;     // 0..7
      const int tl = t & 63;
      mbT[(size_t)(kc * 8 + jl) * 4096 + rb * 64 + tl] = mlds[jl][tl];
    }
    return;
  }
  const int idx = blockIdx.x * 256 + tid;
  const float* s;
  unsigned short* d;
  int i = idx;
  if (y == 0)      { s = q; d = xq; }
  else if (y == 1) { s = k; d = xk; }
  else if (y == 2) { s = v; d = xv; }
  else {
    const int wsel = idx >> 18;
    i = idx & 0x3FFFF;
    s = wsel == 0 ? Wq : (wsel == 1 ? Wk : (wsel == 2 ? Wv : Wo));
    d = wsel == 0 ? wqb : (wsel == 1 ? wkb : (wsel == 2 ? wvb : wob));
  }
  const float4 val = ((const float4*)s)[i];
  ushort4 o;
  o.x = f2bf(val.x); o.y = f2bf(val.y); o.z = f2bf(val.z); o.w = f2bf(val.w);
  ((ushort4*)d)[i] = o;
}

// ---------- 128x128 tile bf16 GEMM: C[M,N] = A[M,K] @ B[N,K]^T (+bias)*cscale ----
template <int BIAS_MODE, int OUT_BF16>
__device__ __forceinline__ void gemm_tile(
    unsigned short* __restrict__ As, unsigned short* __restrict__ Bs,
    const unsigned short* __restrict__ A, const unsigned short* __restrict__ B,
    const float* __restrict__ bias, void* __restrict__ Cp,
    const int N, const int K, const int m0, const int n0, const float cscale) {
  const int tid  = (int)threadIdx.x;
  const int lane = tid & 63;
  const int wm   = tid >> 7;
  const int wn   = (tid >> 6) & 1;

  const f32x4 vzero = {0.f, 0.f, 0.f, 0.f};
  f32x4 acc[4][4];
#pragma unroll
  for (int mr = 0; mr < 4; ++mr)
#pragma unroll
    for (int nr = 0; nr < 4; ++nr) acc[mr][nr] = vzero;

  for (int k0 = 0; k0 < K; k0 += 64) {
#pragma unroll
    for (int i = 0; i < 4; ++i) {
      const int idx = i * 256 + tid;
      const int r = idx >> 3;
      const int c = idx & 7;
      const int koff = k0 + ((c ^ (r & 7)) << 3);
      g2lds16(A + (size_t)(m0 + r) * K + koff, &As[(i * 256 + (tid & 192)) * 8]);
      g2lds16(B + (size_t)(n0 + r) * K + koff, &Bs[(i * 256 + (tid & 192)) * 8]);
    }
    __syncthreads();
#pragma unroll
    for (int kk = 0; kk < 2; ++kk) {
      short8 af[4], bf[4];
#pragma unroll
      for (int mr = 0; mr < 4; ++mr) {
        const int row = wm * 64 + mr * 16 + (lane & 15);
        const int ch = (kk * 4 + (lane >> 4)) ^ (row & 7);
        af[mr] = *(const short8*)&As[row * 64 + ch * 8];
      }
#pragma unroll
      for (int nr = 0; nr < 4; ++nr) {
        const int row = wn * 64 + nr * 16 + (lane & 15);
        const int ch = (kk * 4 + (lane >> 4)) ^ (row & 7);
        bf[nr] = *(const short8*)&Bs[row * 64 + ch * 8];
      }
#pragma unroll
      for (int mr = 0; mr < 4; ++mr)
#pragma unroll
        for (int nr = 0; nr < 4; ++nr)
          acc[mr][nr] = __builtin_amdgcn_mfma_f32_16x16x32_bf16(af[mr], bf[nr],
                                                                acc[mr][nr], 0, 0, 0);
    }
    __syncthreads();
  }

#pragma unroll
  for (int mr = 0; mr < 4; ++mr) {
#pragma unroll
    for (int nr = 0; nr < 4; ++nr) {
#pragma unroll
      for (int rg = 0; rg < 4; ++rg) {
        const int row = m0 + wm * 64 + mr * 16 + ((lane >> 4) << 2) + rg;
        const int col = n0 + wn * 64 + nr * 16 + (lane & 15);
        float v = acc[mr][nr][rg];
        if (BIAS_MODE == 1) v += bias[col];
        if (BIAS_MODE == 2) v += bias[row];
        v *= cscale;
        if (OUT_BF16) ((unsigned short*)Cp)[(size_t)row * N + col] = f2bf(v);
        else          ((float*)Cp)[(size_t)row * N + col] = v;
      }
    }
  }
}

#define QSCALE 0.18033688011112042f  /* 0.125 * log2(e) */
#define LN2    0.6931471805599453f

// flat grid 768, XCD-swizzled: logical = (bid%8)*96 + bid/8.
__global__ __launch_bounds__(256) void proj_qkv(
    const unsigned short* __restrict__ xq, const unsigned short* __restrict__ xk,
    const unsigned short* __restrict__ xv,
    const unsigned short* __restrict__ wq, const unsigned short* __restrict__ wk,
    const unsigned short* __restrict__ wv,
    const float* __restrict__ bq, const float* __restrict__ bk,
    const float* __restrict__ bv,
    unsigned short* __restrict__ qp, unsigned short* __restrict__ kp,
    unsigned short* __restrict__ vt) {
  __shared__ unsigned short As[128 * 64];
  __shared__ unsigned short Bs[128 * 64];
  const int bid = (int)blockIdx.x;
  const int logical = (bid & 7) * 96 + (bid >> 3);
  const int x = logical & 7;        // N-tile
  const int yz = logical >> 3;      // 0..95
  const int y = yz & 31;            // M-tile
  const int z = yz >> 5;            // GEMM select 0..2
  if (z == 0) {
    gemm_tile<1, 1>(As, Bs, xq, wq, bq, qp, 1024, 1024, y * 128, x * 128, QSCALE);
  } else if (z == 1) {
    gemm_tile<1, 1>(As, Bs, xk, wk, bk, kp, 1024, 1024, y * 128, x * 128, 1.0f);
  } else {
    gemm_tile<2, 1>(As, Bs, wv, xv, bv, vt, 4096, 1024, x * 128, y * 128, 1.0f);
  }
}

// ---------- out_proj: 128x128 tile, 8 waves with in-block split-K(2) ----------
// flat grid 256, XCD-swizzled: logical = (bid%8)*32 + bid/8.
__global__ __launch_bounds__(512) void out_proj8(
    const unsigned short* __restrict__ ao, const unsigned short* __restrict__ wo,
    float* __restrict__ out) {
  __shared__ unsigned short SM[4][128 * 64];   // 64 KB

  const int tid  = (int)threadIdx.x;
  const int lane = tid & 63;
  const int wm = tid >> 8;
  const int wn = (tid >> 7) & 1;
  const int kh = (tid >> 6) & 1;
  const int bid = (int)blockIdx.x;
  const int logical = (bid & 7) * 32 + (bid >> 3);
  const int m0 = (logical >> 3) * 128;   // M-tile (A-panel shared by 8 x)
  const int n0 = (logical & 7) * 128;    // N-tile

  const f32x4 vzero = {0.f, 0.f, 0.f, 0.f};
  f32x4 acc[4][4];
#pragma unroll
  for (int mr = 0; mr < 4; ++mr)
#pragma unroll
    for (int nr = 0; nr < 4; ++nr) acc[mr][nr] = vzero;

  for (int j = 0; j < 8; ++j) {
#pragma unroll
    for (int i = 0; i < 2; ++i) {
      const int idx = i * 512 + tid;
      const int r = idx >> 3;
      const int cc = idx & 7;
      const int cs = (cc ^ (r & 7)) << 3;
      const int wb = (i * 512 + (tid & 448)) * 8;
      g2lds16(ao + (size_t)(m0 + r) * 1024 + j * 64 + cs,       &SM[0][wb]);
      g2lds16(ao + (size_t)(m0 + r) * 1024 + 512 + j * 64 + cs, &SM[1][wb]);
      g2lds16(wo + (size_t)(n0 + r) * 1024 + j * 64 + cs,       &SM[2][wb]);
      g2lds16(wo + (size_t)(n0 + r) * 1024 + 512 + j * 64 + cs, &SM[3][wb]);
    }
    __syncthreads();
#pragma unroll
    for (int kk = 0; kk < 2; ++kk) {
      short8 af[4], bf[4];
#pragma unroll
      for (int mr = 0; mr < 4; ++mr) {
        const int row = wm * 64 + mr * 16 + (lane & 15);
        const int ch = (kk * 4 + (lane >> 4)) ^ (row & 7);
        af[mr] = *(const short8*)&SM[kh][row * 64 + ch * 8];
      }
#pragma unroll
      for (int nr = 0; nr < 4; ++nr) {
        const int row = wn * 64 + nr * 16 + (lane & 15);
        const int ch = (kk * 4 + (lane >> 4)) ^ (row & 7);
        bf[nr] = *(const short8*)&SM[2 + kh][row * 64 + ch * 8];
      }
#pragma unroll
      for (int mr = 0; mr < 4; ++mr)
#pragma unroll
        for (int nr = 0; nr < 4; ++nr)
          acc[mr][nr] = __builtin_amdgcn_mfma_f32_16x16x32_bf16(af[mr], bf[nr],
                                                                acc[mr][nr], 0, 0, 0);
    }
    __syncthreads();
  }

  // cross-kh reduce through LDS (bank-rotated, conflict-free)
  float* red = (float*)SM;
  const int reg4 = wm * 2 + wn;
  if (kh) {
#pragma unroll
    for (int mr = 0; mr < 4; ++mr)
#pragma unroll
      for (int nr = 0; nr < 4; ++nr)
#pragma unroll
        for (int g = 0; g < 4; ++g)
          red[reg4 * 4096 + lane * 64 + ((mr * 16 + nr * 4 + g + lane) & 63)] = acc[mr][nr][g];
  }
  __syncthreads();
  if (!kh) {
#pragma unroll
    for (int mr = 0; mr < 4; ++mr)
#pragma unroll
      for (int nr = 0; nr < 4; ++nr)
#pragma unroll
        for (int g = 0; g < 4; ++g) {
          const float v = acc[mr][nr][g] +
              red[reg4 * 4096 + lane * 64 + ((mr * 16 + nr * 4 + g + lane) & 63)];
          const int row = m0 + wm * 64 + mr * 16 + ((lane >> 4) << 2) + g;
          const int col = n0 + wn * 64 + nr * 16 + (lane & 15);
          out[(size_t)row * 1024 + col] = v;
        }
  }
}

// ---------- fused silu-attention: R14 structure + XCD-swizzled flat grid ----
__global__ __launch_bounds__(256, 4) void attn_kernel(
    const unsigned short* __restrict__ qp, const unsigned short* __restrict__ kp,
    const unsigned short* __restrict__ vt, const unsigned int* __restrict__ mbT,
    unsigned short* __restrict__ ao) {
  __shared__ unsigned short SMEM[2][2][64 * 64];   // [buf][K/V][tile] = 32 KB

  const int tid  = (int)threadIdx.x;
  const int lane = tid & 63;
  const int w    = tid >> 6;        // wave 0..3
  const int qsub = w >> 1;          // 0..1
  const int kh   = w & 1;           // k-half of each 64-token tile
  const int c32  = lane & 31;
  const int lo   = lane >> 5;

  const int bid = (int)blockIdx.x;
  const int logical = (bid & 7) * 128 + (bid >> 3);
  const int x  = logical & 31;      // qblk
  const int hb = logical >> 5;      // 0..31
  const int h  = hb & 15;
  const size_t tok0 = (size_t)(hb >> 4) * 2048;
  const int qbase = x * 64;

  // Q as B-fragments: q-row = c32, k(d) = kd*16 + lo*8 + j
  const int q = qbase + qsub * 32 + c32;
  const unsigned short* qptr = qp + (tok0 + q) * 1024 + h * 64 + lo * 8;
  short8 qf[4];
#pragma unroll
  for (int kd = 0; kd < 4; ++kd) qf[kd] = *(const short8*)(qptr + kd * 16);

  // transposed mask: word (kh + 2*kt) at row q; stride 8192 u32 per tile
  const unsigned int* mp = mbT + (size_t)kh * 4096 + tok0 + q;

  f32x16 oacc[2];
#pragma unroll
  for (int dt = 0; dt < 2; ++dt)
#pragma unroll
    for (int r = 0; r < 16; ++r) oacc[dt][r] = 0.f;

  // ---- precomputed staging addresses (2 chunks per thread per tile) ----
  const int rr = tid >> 3, ccc = tid & 7;
  const int cs = (ccc ^ (rr & 7)) << 3;
  const unsigned short* kg0 = kp + (tok0 + rr) * 1024 + h * 64 + cs;
  const unsigned short* kg1 = kg0 + 32 * 1024;
  const unsigned short* vg0 = vt + (size_t)(h * 64 + rr) * 4096 + tok0 + cs;
  const unsigned short* vg1 = vg0 + (size_t)32 * 4096;
  const int wbo = (tid & 192) * 8;
  unsigned short* const kl0a = &SMEM[0][0][wbo];
  unsigned short* const kl1a = &SMEM[0][0][2048 + wbo];
  unsigned short* const vl0a = &SMEM[0][1][wbo];
  unsigned short* const vl1a = &SMEM[0][1][2048 + wbo];
  unsigned short* const kl0b = &SMEM[1][0][wbo];
  unsigned short* const kl1b = &SMEM[1][0][2048 + wbo];
  unsigned short* const vl0b = &SMEM[1][1][wbo];
  unsigned short* const vl1b = &SMEM[1][1][2048 + wbo];

  // ---- precomputed LDS read offsets (elements; loop-invariant) ----
  int qko[4], pvo[4];
#pragma unroll
  for (int kd = 0; kd < 4; ++kd)
    qko[kd] = (kh * 32 + c32) * 64 + (((2 * kd + lo) ^ (c32 & 7)) << 3);
  pvo[0] = c32 * 64 + (((4 * kh + lo) ^ (c32 & 7)) << 3);
  pvo[1] = c32 * 64 + (((4 * kh + 2 + lo) ^ (c32 & 7)) << 3);
  pvo[2] = (32 + c32) * 64 + (((4 * kh + lo) ^ (c32 & 7)) << 3);
  pvo[3] = (32 + c32) * 64 + (((4 * kh + 2 + lo) ^ (c32 & 7)) << 3);

  const unsigned short* const K0 = &SMEM[0][0][0];
  const unsigned short* const V0 = &SMEM[0][1][0];
  const unsigned short* const K1 = &SMEM[1][0][0];
  const unsigned short* const V1 = &SMEM[1][1][0];

  const f32x16 z16 = {0.f};

  auto compute = [&](const unsigned short* Kb, const unsigned short* Vb,
                     unsigned int mcur) {
    f32x16 st = z16;
    __builtin_amdgcn_s_setprio(1);
    st = __builtin_amdgcn_mfma_f32_32x32x16_bf16(*(const short8*)(Kb + qko[0]), qf[0], st, 0, 0, 0);
    st = __builtin_amdgcn_mfma_f32_32x32x16_bf16(*(const short8*)(Kb + qko[1]), qf[1], st, 0, 0, 0);
    st = __builtin_amdgcn_mfma_f32_32x32x16_bf16(*(const short8*)(Kb + qko[2]), qf[2], st, 0, 0, 0);
    st = __builtin_amdgcn_mfma_f32_32x32x16_bf16(*(const short8*)(Kb + qko[3]), qf[3], st, 0, 0, 0);
    __builtin_amdgcn_s_setprio(0);

    const unsigned int ms = mcur >> (lo * 4);
#pragma unroll
    for (int r = 0; r < 16; ++r) {
      const int krow = (r & 3) + 8 * (r >> 2);
      const int smear = __builtin_amdgcn_sbfe((int)ms, krow, 1);  // 0 or -1
      const float sv = __int_as_float(__float_as_int(st[r]) & smear);
      st[r] = sv * __builtin_amdgcn_rcpf(1.f + __builtin_amdgcn_exp2f(-sv));
    }

    unsigned int u[8];
#pragma unroll
    for (int g = 0; g < 4; ++g) {
      asm("v_cvt_pk_bf16_f32 %0, %1, %2" : "=v"(u[2 * g])     : "v"(st[4 * g]),     "v"(st[4 * g + 1]));
      asm("v_cvt_pk_bf16_f32 %0, %1, %2" : "=v"(u[2 * g + 1]) : "v"(st[4 * g + 2]), "v"(st[4 * g + 3]));
    }
    asm("v_permlane32_swap_b32 %0, %1" : "+v"(u[0]), "+v"(u[2]));
    asm("v_permlane32_swap_b32 %0, %1" : "+v"(u[1]), "+v"(u[3]));
    asm("v_permlane32_swap_b32 %0, %1" : "+v"(u[4]), "+v"(u[6]));
    asm("v_permlane32_swap_b32 %0, %1" : "+v"(u[5]), "+v"(u[7]));
    const uint4v wA = {u[0], u[1], u[2], u[3]};
    const uint4v wB = {u[4], u[5], u[6], u[7]};
    const short8 paA = __builtin_bit_cast(short8, wA);
    const short8 paB = __builtin_bit_cast(short8, wB);

    __builtin_amdgcn_s_setprio(1);
    oacc[0] = __builtin_amdgcn_mfma_f32_32x32x16_bf16(paA, *(const short8*)(Vb + pvo[0]), oacc[0], 0, 0, 0);
    oacc[0] = __builtin_amdgcn_mfma_f32_32x32x16_bf16(paB, *(const short8*)(Vb + pvo[1]), oacc[0], 0, 0, 0);
    oacc[1] = __builtin_amdgcn_mfma_f32_32x32x16_bf16(paA, *(const short8*)(Vb + pvo[2]), oacc[1], 0, 0, 0);
    oacc[1] = __builtin_amdgcn_mfma_f32_32x32x16_bf16(paB, *(const short8*)(Vb + pvo[3]), oacc[1], 0, 0, 0);
    __builtin_amdgcn_s_setprio(0);
  };

  // prologue: tile 0 into buf A
  g2lds16(kg0, kl0a); g2lds16(kg1, kl1a);
  g2lds16(vg0, vl0a); g2lds16(vg1, vl1a);
  __syncthreads();

  for (int kt2 = 0; kt2 < 16; ++kt2) {
    const int kt = kt2 * 2;
    const unsigned int mA = mp[0];
    const unsigned int mB = mp[8192];
    mp += 16384;

    // stage kt+1 into buf B, compute kt from buf A
    {
      const size_t ko = (size_t)(kt + 1) * 65536;
      const int vo = (kt + 1) * 64;
      g2lds16(kg0 + ko, kl0b); g2lds16(kg1 + ko, kl1b);
      g2lds16(vg0 + vo, vl0b); g2lds16(vg1 + vo, vl1b);
    }
    compute(K0, V0, mA);
    __syncthreads();

    // stage kt+2 into buf A, compute kt+1 from buf B
    if (kt2 < 15) {
      const size_t ko = (size_t)(kt + 2) * 65536;
      const int vo = (kt + 2) * 64;
      g2lds16(kg0 + ko, kl0a); g2lds16(kg1 + ko, kl1a);
      g2lds16(vg0 + vo, vl0a); g2lds16(vg1 + vo, vl1a);
    }
    compute(K1, V1, mB);
    __syncthreads();
  }

  // cross-kh reduce through LDS (bank-rotated, conflict-free), then store
  float* red = (float*)SMEM;
  const int rbase = qsub * 2048;
  if (kh) {
#pragma unroll
    for (int dt = 0; dt < 2; ++dt)
#pragma unroll
      for (int r = 0; r < 16; ++r)
        red[rbase + lane * 32 + ((dt * 16 + r + lane) & 31)] = oacc[dt][r];
  }
  __syncthreads();
  if (!kh) {
#pragma unroll
    for (int dt = 0; dt < 2; ++dt)
#pragma unroll
      for (int r = 0; r < 16; ++r) {
        const float o2 = oacc[dt][r] + red[rbase + lane * 32 + ((dt * 16 + r + lane) & 31)];
        const int row = qbase + qsub * 32 + (r & 3) + 8 * (r >> 2) + 4 * lo;
        const int col = h * 64 + dt * 32 + c32;
        ao[(tok0 + row) * 1024 + col] = f2bf(o2 * LN2);
      }
  }
}

// ---------- launcher ----------
extern "C" void kernel_launch(void* const* d_in, const int* in_sizes, int n_in,
                              void* d_out, int out_size, void* d_ws, size_t ws_size,
                              hipStream_t stream) {
  (void)in_sizes; (void)n_in; (void)out_size; (void)ws_size;
  const float* query = (const float*)d_in[0];
  const float* key   = (const float*)d_in[1];
  const float* value = (const float*)d_in[2];
  const int*   mask  = (const int*)d_in[3];
  const float* Wq = (const float*)d_in[4];
  const float* bq = (const float*)d_in[5];
  const float* Wk = (const float*)d_in[6];
  const float* bk = (const float*)d_in[7];
  const float* Wv = (const float*)d_in[8];
  const float* bv = (const float*)d_in[9];
  const float* Wo = (const float*)d_in[10];

  char* ws = (char*)d_ws;
  const size_t MB = 1024 * 1024;
  unsigned short* xq  = (unsigned short*)(ws + 0 * MB);   // dead after proj -> ao
  unsigned short* xk  = (unsigned short*)(ws + 8 * MB);
  unsigned short* xv  = (unsigned short*)(ws + 16 * MB);
  unsigned short* wqb = (unsigned short*)(ws + 24 * MB);
  unsigned short* wkb = (unsigned short*)(ws + 26 * MB);
  unsigned short* wvb = (unsigned short*)(ws + 28 * MB);
  unsigned short* wob = (unsigned short*)(ws + 30 * MB);
  unsigned short* qp  = (unsigned short*)(ws + 32 * MB);
  unsigned short* kp  = (unsigned short*)(ws + 40 * MB);
  unsigned short* vt  = (unsigned short*)(ws + 48 * MB);
  unsigned int*   mbT = (unsigned int*)(ws + 56 * MB);    // 1 MB transposed mask
  unsigned short* ao  = xq;    // final attn output (reuse xq slot)

  prep<<<dim3(4096, 5), 256, 0, stream>>>(query, key, value, Wq, Wk, Wv, Wo, mask,
                                          xq, xk, xv, wqb, wkb, wvb, wob, mbT);

  proj_qkv<<<dim3(768), 256, 0, stream>>>(xq, xk, xv, wqb, wkb, wvb,
                                          bq, bk, bv, qp, kp, vt);
  attn_kernel<<<dim3(1024), 256, 0, stream>>>(qp, kp, vt, mbT, ao);
  out_proj8<<<dim3(256), 512, 0, stream>>>(ao, wob, (float*)d_out);
}

// Round 17
// 148.544 us; speedup vs baseline: 1.0875x; 1.0875x over previous
//
#include <hip/hip_runtime.h>
#include <hip/hip_bf16.h>

typedef __attribute__((ext_vector_type(4))) float f32x4;
typedef __attribute__((ext_vector_type(16))) float f32x16;
typedef __attribute__((ext_vector_type(8))) short short8;
typedef __attribute__((ext_vector_type(4))) unsigned int uint4v;

// ---------- helpers ----------
__device__ __forceinline__ unsigned short f2bf(float f) {
  unsigned int u = __float_as_uint(f);
  u += 0x7fffu + ((u >> 16) & 1u);   // RNE
  return (unsigned short)(u >> 16);
}

__device__ __forceinline__ void g2lds16(const void* g, void* l) {
  __builtin_amdgcn_global_load_lds(
      (const __attribute__((address_space(1))) void*)g,
      (__attribute__((address_space(3))) void*)l, 16, 0, 0);
}

// ---------- fused prep: f32->bf16 converts + transposed mask bit-pack ----------
// R15 version restored: the scattered 4B mbT stores are L2-absorbed (mbT = 1MB)
// — R16's "coalesced" LDS-transpose rewrite was latency-bound and 13us slower.
__global__ __launch_bounds__(256) void prep(
    const float* __restrict__ q, const float* __restrict__ k,
    const float* __restrict__ v, const float* __restrict__ Wq,
    const float* __restrict__ Wk, const float* __restrict__ Wv,
    const float* __restrict__ Wo, const int* __restrict__ mask,
    unsigned short* __restrict__ xq, unsigned short* __restrict__ xk,
    unsigned short* __restrict__ xv, unsigned short* __restrict__ wqb,
    unsigned short* __restrict__ wkb, unsigned short* __restrict__ wvb,
    unsigned short* __restrict__ wob, unsigned int* __restrict__ mbT) {
  const int y = blockIdx.y;
  const int idx = blockIdx.x * 256 + (int)threadIdx.x;
  if (y == 4) {
#pragma unroll
    for (int it = 0; it < 8; ++it) {
      const int i = blockIdx.x * 2048 + it * 256 + (int)threadIdx.x;
      const unsigned long long bits = __ballot(mask[i] != 0);
      if ((threadIdx.x & 63) == 0) {
        const int row = i >> 11;
        const int j = (i & 2047) >> 5;
        mbT[j * 4096 + row] = (unsigned int)bits;
        mbT[(j + 1) * 4096 + row] = (unsigned int)(bits >> 32);
      }
    }
    return;
  }
  const float* s;
  unsigned short* d;
  int i = idx;
  if (y == 0)      { s = q; d = xq; }
  else if (y == 1) { s = k; d = xk; }
  else if (y == 2) { s = v; d = xv; }
  else {
    const int wsel = idx >> 18;
    i = idx & 0x3FFFF;
    s = wsel == 0 ? Wq : (wsel == 1 ? Wk : (wsel == 2 ? Wv : Wo));
    d = wsel == 0 ? wqb : (wsel == 1 ? wkb : (wsel == 2 ? wvb : wob));
  }
  const float4 val = ((const float4*)s)[i];
  ushort4 o;
  o.x = f2bf(val.x); o.y = f2bf(val.y); o.z = f2bf(val.z); o.w = f2bf(val.w);
  ((ushort4*)d)[i] = o;
}

// ---------- 128x128 tile bf16 GEMM: C[M,N] = A[M,K] @ B[N,K]^T (+bias)*cscale ----
template <int BIAS_MODE, int OUT_BF16>
__device__ __forceinline__ void gemm_tile(
    unsigned short* __restrict__ As, unsigned short* __restrict__ Bs,
    const unsigned short* __restrict__ A, const unsigned short* __restrict__ B,
    const float* __restrict__ bias, void* __restrict__ Cp,
    const int N, const int K, const int m0, const int n0, const float cscale) {
  const int tid  = (int)threadIdx.x;
  const int lane = tid & 63;
  const int wm   = tid >> 7;
  const int wn   = (tid >> 6) & 1;

  const f32x4 vzero = {0.f, 0.f, 0.f, 0.f};
  f32x4 acc[4][4];
#pragma unroll
  for (int mr = 0; mr < 4; ++mr)
#pragma unroll
    for (int nr = 0; nr < 4; ++nr) acc[mr][nr] = vzero;

  for (int k0 = 0; k0 < K; k0 += 64) {
#pragma unroll
    for (int i = 0; i < 4; ++i) {
      const int idx = i * 256 + tid;
      const int r = idx >> 3;
      const int c = idx & 7;
      const int koff = k0 + ((c ^ (r & 7)) << 3);
      g2lds16(A + (size_t)(m0 + r) * K + koff, &As[(i * 256 + (tid & 192)) * 8]);
      g2lds16(B + (size_t)(n0 + r) * K + koff, &Bs[(i * 256 + (tid & 192)) * 8]);
    }
    __syncthreads();
#pragma unroll
    for (int kk = 0; kk < 2; ++kk) {
      short8 af[4], bf[4];
#pragma unroll
      for (int mr = 0; mr < 4; ++mr) {
        const int row = wm * 64 + mr * 16 + (lane & 15);
        const int ch = (kk * 4 + (lane >> 4)) ^ (row & 7);
        af[mr] = *(const short8*)&As[row * 64 + ch * 8];
      }
#pragma unroll
      for (int nr = 0; nr < 4; ++nr) {
        const int row = wn * 64 + nr * 16 + (lane & 15);
        const int ch = (kk * 4 + (lane >> 4)) ^ (row & 7);
        bf[nr] = *(const short8*)&Bs[row * 64 + ch * 8];
      }
#pragma unroll
      for (int mr = 0; mr < 4; ++mr)
#pragma unroll
        for (int nr = 0; nr < 4; ++nr)
          acc[mr][nr] = __builtin_amdgcn_mfma_f32_16x16x32_bf16(af[mr], bf[nr],
                                                                acc[mr][nr], 0, 0, 0);
    }
    __syncthreads();
  }

#pragma unroll
  for (int mr = 0; mr < 4; ++mr) {
#pragma unroll
    for (int nr = 0; nr < 4; ++nr) {
#pragma unroll
      for (int rg = 0; rg < 4; ++rg) {
        const int row = m0 + wm * 64 + mr * 16 + ((lane >> 4) << 2) + rg;
        const int col = n0 + wn * 64 + nr * 16 + (lane & 15);
        float v = acc[mr][nr][rg];
        if (BIAS_MODE == 1) v += bias[col];
        if (BIAS_MODE == 2) v += bias[row];
        v *= cscale;
        if (OUT_BF16) ((unsigned short*)Cp)[(size_t)row * N + col] = f2bf(v);
        else          ((float*)Cp)[(size_t)row * N + col] = v;
      }
    }
  }
}

#define QSCALE 0.18033688011112042f  /* 0.125 * log2(e) */
#define LN2    0.6931471805599453f

// flat grid 768, XCD-swizzled: logical = (bid%8)*96 + bid/8.
__global__ __launch_bounds__(256) void proj_qkv(
    const unsigned short* __restrict__ xq, const unsigned short* __restrict__ xk,
    const unsigned short* __restrict__ xv,
    const unsigned short* __restrict__ wq, const unsigned short* __restrict__ wk,
    const unsigned short* __restrict__ wv,
    const float* __restrict__ bq, const float* __restrict__ bk,
    const float* __restrict__ bv,
    unsigned short* __restrict__ qp, unsigned short* __restrict__ kp,
    unsigned short* __restrict__ vt) {
  __shared__ unsigned short As[128 * 64];
  __shared__ unsigned short Bs[128 * 64];
  const int bid = (int)blockIdx.x;
  const int logical = (bid & 7) * 96 + (bid >> 3);
  const int x = logical & 7;        // N-tile
  const int yz = logical >> 3;      // 0..95
  const int y = yz & 31;            // M-tile
  const int z = yz >> 5;            // GEMM select 0..2
  if (z == 0) {
    gemm_tile<1, 1>(As, Bs, xq, wq, bq, qp, 1024, 1024, y * 128, x * 128, QSCALE);
  } else if (z == 1) {
    gemm_tile<1, 1>(As, Bs, xk, wk, bk, kp, 1024, 1024, y * 128, x * 128, 1.0f);
  } else {
    gemm_tile<2, 1>(As, Bs, wv, xv, bv, vt, 4096, 1024, x * 128, y * 128, 1.0f);
  }
}

// ---------- out_proj: 128x128 tile, 8 waves with in-block split-K(2) ----------
// flat grid 256, XCD-swizzled: logical = (bid%8)*32 + bid/8.
__global__ __launch_bounds__(512) void out_proj8(
    const unsigned short* __restrict__ ao, const unsigned short* __restrict__ wo,
    float* __restrict__ out) {
  __shared__ unsigned short SM[4][128 * 64];   // 64 KB

  const int tid  = (int)threadIdx.x;
  const int lane = tid & 63;
  const int wm = tid >> 8;
  const int wn = (tid >> 7) & 1;
  const int kh = (tid >> 6) & 1;
  const int bid = (int)blockIdx.x;
  const int logical = (bid & 7) * 32 + (bid >> 3);
  const int m0 = (logical >> 3) * 128;   // M-tile (A-panel shared by 8 x)
  const int n0 = (logical & 7) * 128;    // N-tile

  const f32x4 vzero = {0.f, 0.f, 0.f, 0.f};
  f32x4 acc[4][4];
#pragma unroll
  for (int mr = 0; mr < 4; ++mr)
#pragma unroll
    for (int nr = 0; nr < 4; ++nr) acc[mr][nr] = vzero;

  for (int j = 0; j < 8; ++j) {
#pragma unroll
    for (int i = 0; i < 2; ++i) {
      const int idx = i * 512 + tid;
      const int r = idx >> 3;
      const int cc = idx & 7;
      const int cs = (cc ^ (r & 7)) << 3;
      const int wb = (i * 512 + (tid & 448)) * 8;
      g2lds16(ao + (size_t)(m0 + r) * 1024 + j * 64 + cs,       &SM[0][wb]);
      g2lds16(ao + (size_t)(m0 + r) * 1024 + 512 + j * 64 + cs, &SM[1][wb]);
      g2lds16(wo + (size_t)(n0 + r) * 1024 + j * 64 + cs,       &SM[2][wb]);
      g2lds16(wo + (size_t)(n0 + r) * 1024 + 512 + j * 64 + cs, &SM[3][wb]);
    }
    __syncthreads();
#pragma unroll
    for (int kk = 0; kk < 2; ++kk) {
      short8 af[4], bf[4];
#pragma unroll
      for (int mr = 0; mr < 4; ++mr) {
        const int row = wm * 64 + mr * 16 + (lane & 15);
        const int ch = (kk * 4 + (lane >> 4)) ^ (row & 7);
        af[mr] = *(const short8*)&SM[kh][row * 64 + ch * 8];
      }
#pragma unroll
      for (int nr = 0; nr < 4; ++nr) {
        const int row = wn * 64 + nr * 16 + (lane & 15);
        const int ch = (kk * 4 + (lane >> 4)) ^ (row & 7);
        bf[nr] = *(const short8*)&SM[2 + kh][row * 64 + ch * 8];
      }
#pragma unroll
      for (int mr = 0; mr < 4; ++mr)
#pragma unroll
        for (int nr = 0; nr < 4; ++nr)
          acc[mr][nr] = __builtin_amdgcn_mfma_f32_16x16x32_bf16(af[mr], bf[nr],
                                                                acc[mr][nr], 0, 0, 0);
    }
    __syncthreads();
  }

  // cross-kh reduce through LDS (bank-rotated, conflict-free)
  float* red = (float*)SM;
  const int reg4 = wm * 2 + wn;
  if (kh) {
#pragma unroll
    for (int mr = 0; mr < 4; ++mr)
#pragma unroll
      for (int nr = 0; nr < 4; ++nr)
#pragma unroll
        for (int g = 0; g < 4; ++g)
          red[reg4 * 4096 + lane * 64 + ((mr * 16 + nr * 4 + g + lane) & 63)] = acc[mr][nr][g];
  }
  __syncthreads();
  if (!kh) {
#pragma unroll
    for (int mr = 0; mr < 4; ++mr)
#pragma unroll
      for (int nr = 0; nr < 4; ++nr)
#pragma unroll
        for (int g = 0; g < 4; ++g) {
          const float v = acc[mr][nr][g] +
              red[reg4 * 4096 + lane * 64 + ((mr * 16 + nr * 4 + g + lane) & 63)];
          const int row = m0 + wm * 64 + mr * 16 + ((lane >> 4) << 2) + g;
          const int col = n0 + wn * 64 + nr * 16 + (lane & 15);
          out[(size_t)row * 1024 + col] = v;
        }
  }
}

// ---------- fused silu-attention: R14 structure + XCD-swizzled flat grid ----
__global__ __launch_bounds__(256, 4) void attn_kernel(
    const unsigned short* __restrict__ qp, const unsigned short* __restrict__ kp,
    const unsigned short* __restrict__ vt, const unsigned int* __restrict__ mbT,
    unsigned short* __restrict__ ao) {
  __shared__ unsigned short SMEM[2][2][64 * 64];   // [buf][K/V][tile] = 32 KB

  const int tid  = (int)threadIdx.x;
  const int lane = tid & 63;
  const int w    = tid >> 6;        // wave 0..3
  const int qsub = w >> 1;          // 0..1
  const int kh   = w & 1;           // k-half of each 64-token tile
  const int c32  = lane & 31;
  const int lo   = lane >> 5;

  const int bid = (int)blockIdx.x;
  const int logical = (bid & 7) * 128 + (bid >> 3);
  const int x  = logical & 31;      // qblk
  const int hb = logical >> 5;      // 0..31
  const int h  = hb & 15;
  const size_t tok0 = (size_t)(hb >> 4) * 2048;
  const int qbase = x * 64;

  // Q as B-fragments: q-row = c32, k(d) = kd*16 + lo*8 + j
  const int q = qbase + qsub * 32 + c32;
  const unsigned short* qptr = qp + (tok0 + q) * 1024 + h * 64 + lo * 8;
  short8 qf[4];
#pragma unroll
  for (int kd = 0; kd < 4; ++kd) qf[kd] = *(const short8*)(qptr + kd * 16);

  // transposed mask: word (kh + 2*kt) at row q; stride 8192 u32 per tile
  const unsigned int* mp = mbT + (size_t)kh * 4096 + tok0 + q;

  f32x16 oacc[2];
#pragma unroll
  for (int dt = 0; dt < 2; ++dt)
#pragma unroll
    for (int r = 0; r < 16; ++r) oacc[dt][r] = 0.f;

  // ---- precomputed staging addresses (2 chunks per thread per tile) ----
  const int rr = tid >> 3, ccc = tid & 7;
  const int cs = (ccc ^ (rr & 7)) << 3;
  const unsigned short* kg0 = kp + (tok0 + rr) * 1024 + h * 64 + cs;
  const unsigned short* kg1 = kg0 + 32 * 1024;
  const unsigned short* vg0 = vt + (size_t)(h * 64 + rr) * 4096 + tok0 + cs;
  const unsigned short* vg1 = vg0 + (size_t)32 * 4096;
  const int wbo = (tid & 192) * 8;
  unsigned short* const kl0a = &SMEM[0][0][wbo];
  unsigned short* const kl1a = &SMEM[0][0][2048 + wbo];
  unsigned short* const vl0a = &SMEM[0][1][wbo];
  unsigned short* const vl1a = &SMEM[0][1][2048 + wbo];
  unsigned short* const kl0b = &SMEM[1][0][wbo];
  unsigned short* const kl1b = &SMEM[1][0][2048 + wbo];
  unsigned short* const vl0b = &SMEM[1][1][wbo];
  unsigned short* const vl1b = &SMEM[1][1][2048 + wbo];

  // ---- precomputed LDS read offsets (elements; loop-invariant) ----
  int qko[4], pvo[4];
#pragma unroll
  for (int kd = 0; kd < 4; ++kd)
    qko[kd] = (kh * 32 + c32) * 64 + (((2 * kd + lo) ^ (c32 & 7)) << 3);
  pvo[0] = c32 * 64 + (((4 * kh + lo) ^ (c32 & 7)) << 3);
  pvo[1] = c32 * 64 + (((4 * kh + 2 + lo) ^ (c32 & 7)) << 3);
  pvo[2] = (32 + c32) * 64 + (((4 * kh + lo) ^ (c32 & 7)) << 3);
  pvo[3] = (32 + c32) * 64 + (((4 * kh + 2 + lo) ^ (c32 & 7)) << 3);

  const unsigned short* const K0 = &SMEM[0][0][0];
  const unsigned short* const V0 = &SMEM[0][1][0];
  const unsigned short* const K1 = &SMEM[1][0][0];
  const unsigned short* const V1 = &SMEM[1][1][0];

  const f32x16 z16 = {0.f};

  auto compute = [&](const unsigned short* Kb, const unsigned short* Vb,
                     unsigned int mcur) {
    f32x16 st = z16;
    __builtin_amdgcn_s_setprio(1);
    st = __builtin_amdgcn_mfma_f32_32x32x16_bf16(*(const short8*)(Kb + qko[0]), qf[0], st, 0, 0, 0);
    st = __builtin_amdgcn_mfma_f32_32x32x16_bf16(*(const short8*)(Kb + qko[1]), qf[1], st, 0, 0, 0);
    st = __builtin_amdgcn_mfma_f32_32x32x16_bf16(*(const short8*)(Kb + qko[2]), qf[2], st, 0, 0, 0);
    st = __builtin_amdgcn_mfma_f32_32x32x16_bf16(*(const short8*)(Kb + qko[3]), qf[3], st, 0, 0, 0);
    __builtin_amdgcn_s_setprio(0);

    const unsigned int ms = mcur >> (lo * 4);
#pragma unroll
    for (int r = 0; r < 16; ++r) {
      const int krow = (r & 3) + 8 * (r >> 2);
      const int smear = __builtin_amdgcn_sbfe((int)ms, krow, 1);  // 0 or -1
      const float sv = __int_as_float(__float_as_int(st[r]) & smear);
      st[r] = sv * __builtin_amdgcn_rcpf(1.f + __builtin_amdgcn_exp2f(-sv));
    }

    unsigned int u[8];
#pragma unroll
    for (int g = 0; g < 4; ++g) {
      asm("v_cvt_pk_bf16_f32 %0, %1, %2" : "=v"(u[2 * g])     : "v"(st[4 * g]),     "v"(st[4 * g + 1]));
      asm("v_cvt_pk_bf16_f32 %0, %1, %2" : "=v"(u[2 * g + 1]) : "v"(st[4 * g + 2]), "v"(st[4 * g + 3]));
    }
    asm("v_permlane32_swap_b32 %0, %1" : "+v"(u[0]), "+v"(u[2]));
    asm("v_permlane32_swap_b32 %0, %1" : "+v"(u[1]), "+v"(u[3]));
    asm("v_permlane32_swap_b32 %0, %1" : "+v"(u[4]), "+v"(u[6]));
    asm("v_permlane32_swap_b32 %0, %1" : "+v"(u[5]), "+v"(u[7]));
    const uint4v wA = {u[0], u[1], u[2], u[3]};
    const uint4v wB = {u[4], u[5], u[6], u[7]};
    const short8 paA = __builtin_bit_cast(short8, wA);
    const short8 paB = __builtin_bit_cast(short8, wB);

    __builtin_amdgcn_s_setprio(1);
    oacc[0] = __builtin_amdgcn_mfma_f32_32x32x16_bf16(paA, *(const short8*)(Vb + pvo[0]), oacc[0], 0, 0, 0);
    oacc[0] = __builtin_amdgcn_mfma_f32_32x32x16_bf16(paB, *(const short8*)(Vb + pvo[1]), oacc[0], 0, 0, 0);
    oacc[1] = __builtin_amdgcn_mfma_f32_32x32x16_bf16(paA, *(const short8*)(Vb + pvo[2]), oacc[1], 0, 0, 0);
    oacc[1] = __builtin_amdgcn_mfma_f32_32x32x16_bf16(paB, *(const short8*)(Vb + pvo[3]), oacc[1], 0, 0, 0);
    __builtin_amdgcn_s_setprio(0);
  };

  // prologue: tile 0 into buf A
  g2lds16(kg0, kl0a); g2lds16(kg1, kl1a);
  g2lds16(vg0, vl0a); g2lds16(vg1, vl1a);
  __syncthreads();

  for (int kt2 = 0; kt2 < 16; ++kt2) {
    const int kt = kt2 * 2;
    const unsigned int mA = mp[0];
    const unsigned int mB = mp[8192];
    mp += 16384;

    // stage kt+1 into buf B, compute kt from buf A
    {
      const size_t ko = (size_t)(kt + 1) * 65536;
      const int vo = (kt + 1) * 64;
      g2lds16(kg0 + ko, kl0b); g2lds16(kg1 + ko, kl1b);
      g2lds16(vg0 + vo, vl0b); g2lds16(vg1 + vo, vl1b);
    }
    compute(K0, V0, mA);
    __syncthreads();

    // stage kt+2 into buf A, compute kt+1 from buf B
    if (kt2 < 15) {
      const size_t ko = (size_t)(kt + 2) * 65536;
      const int vo = (kt + 2) * 64;
      g2lds16(kg0 + ko, kl0a); g2lds16(kg1 + ko, kl1a);
      g2lds16(vg0 + vo, vl0a); g2lds16(vg1 + vo, vl1a);
    }
    compute(K1, V1, mB);
    __syncthreads();
  }

  // cross-kh reduce through LDS (bank-rotated, conflict-free), then store
  float* red = (float*)SMEM;
  const int rbase = qsub * 2048;
  if (kh) {
#pragma unroll
    for (int dt = 0; dt < 2; ++dt)
#pragma unroll
      for (int r = 0; r < 16; ++r)
        red[rbase + lane * 32 + ((dt * 16 + r + lane) & 31)] = oacc[dt][r];
  }
  __syncthreads();
  if (!kh) {
#pragma unroll
    for (int dt = 0; dt < 2; ++dt)
#pragma unroll
      for (int r = 0; r < 16; ++r) {
        const float o2 = oacc[dt][r] + red[rbase + lane * 32 + ((dt * 16 + r + lane) & 31)];
        const int row = qbase + qsub * 32 + (r & 3) + 8 * (r >> 2) + 4 * lo;
        const int col = h * 64 + dt * 32 + c32;
        ao[(tok0 + row) * 1024 + col] = f2bf(o2 * LN2);
      }
  }
}

// ---------- launcher ----------
extern "C" void kernel_launch(void* const* d_in, const int* in_sizes, int n_in,
                              void* d_out, int out_size, void* d_ws, size_t ws_size,
                              hipStream_t stream) {
  (void)in_sizes; (void)n_in; (void)out_size; (void)ws_size;
  const float* query = (const float*)d_in[0];
  const float* key   = (const float*)d_in[1];
  const float* value = (const float*)d_in[2];
  const int*   mask  = (const int*)d_in[3];
  const float* Wq = (const float*)d_in[4];
  const float* bq = (const float*)d_in[5];
  const float* Wk = (const float*)d_in[6];
  const float* bk = (const float*)d_in[7];
  const float* Wv = (const float*)d_in[8];
  const float* bv = (const float*)d_in[9];
  const float* Wo = (const float*)d_in[10];

  char* ws = (char*)d_ws;
  const size_t MB = 1024 * 1024;
  unsigned short* xq  = (unsigned short*)(ws + 0 * MB);   // dead after proj -> ao
  unsigned short* xk  = (unsigned short*)(ws + 8 * MB);
  unsigned short* xv  = (unsigned short*)(ws + 16 * MB);
  unsigned short* wqb = (unsigned short*)(ws + 24 * MB);
  unsigned short* wkb = (unsigned short*)(ws + 26 * MB);
  unsigned short* wvb = (unsigned short*)(ws + 28 * MB);
  unsigned short* wob = (unsigned short*)(ws + 30 * MB);
  unsigned short* qp  = (unsigned short*)(ws + 32 * MB);
  unsigned short* kp  = (unsigned short*)(ws + 40 * MB);
  unsigned short* vt  = (unsigned short*)(ws + 48 * MB);
  unsigned int*   mbT = (unsigned int*)(ws + 56 * MB);    // 1 MB transposed mask
  unsigned short* ao  = xq;    // final attn output (reuse xq slot)

  prep<<<dim3(4096, 5), 256, 0, stream>>>(query, key, value, Wq, Wk, Wv, Wo, mask,
                                          xq, xk, xv, wqb, wkb, wvb, wob, mbT);

  proj_qkv<<<dim3(768), 256, 0, stream>>>(xq, xk, xv, wqb, wkb, wvb,
                                          bq, bk, bv, qp, kp, vt);
  attn_kernel<<<dim3(1024), 256, 0, stream>>>(qp, kp, vt, mbT, ao);
  out_proj8<<<dim3(256), 512, 0, stream>>>(ao, wob, (float*)d_out);
}